// Round 1
// baseline (404.555 us; speedup 1.0000x reference)
//
#include <hip/hip_runtime.h>
#include <math.h>

// Problem constants
// B=4, GL=4, GF=128, N=1024, CS=32, CN=16, NA=16, S=512, HS=512
//
// Derived flat sizes (fp32 elements):
//  X per b     : 512*1024            (k = l'*128+f)
//  U/P2 per b  : 128*1024 = 131072   (rows m=0..1023 of 128 when viewed as p)
//  S/V per b   : 1024*512 = 524288   ([m][ju], ju = j*32+u)
//  Cw per b    : 512*128  = 65536    ([ju][q], q = k*32+i)

static constexpr int OFF_U  = 0;
static constexpr int OFF_P2 = 524288;
static constexpr int OFF_S  = 1048576;
static constexpr int OFF_CW = 3145728;
static constexpr int OFF_SS = 3407872;   // 16
static constexpr int OFF_BG = 3407888;   // 2048
static constexpr int OFF_G  = 3409936;   // 2048
static constexpr int OFF_VA = 3411984;   // 2048

// ---------------------------------------------------------------------------
// K1: U[b][l*32+c][n] = sum_k Wp[(l*32+c)][k] * X[b][k][n] + bp[l*32+c]
//     + per-(b,l) sum of squares into SS (atomic)
// grid (8 ct, 4 l, 4 b), 256 threads, each thread 4 c x 4 n (float4)
__global__ void k_primary(const float* __restrict__ X, const float* __restrict__ Wp,
                          const float* __restrict__ bp, float* __restrict__ U,
                          float* __restrict__ SS)
{
    const int ct = blockIdx.x, l = blockIdx.y, b = blockIdx.z;
    const int t = threadIdx.x;
    const int n = t * 4;
    float4 acc[4];
#pragma unroll
    for (int cc = 0; cc < 4; ++cc) acc[cc] = make_float4(0.f, 0.f, 0.f, 0.f);
    const float* xb = X + (size_t)b * (512 * 1024) + n;
    const float* wr = Wp + (size_t)(l * 32 + ct * 4) * 512;
    for (int k = 0; k < 512; ++k) {
        const float4 xv = *(const float4*)(xb + (size_t)k * 1024);
#pragma unroll
        for (int cc = 0; cc < 4; ++cc) {
            const float w = wr[cc * 512 + k];
            acc[cc].x = fmaf(w, xv.x, acc[cc].x);
            acc[cc].y = fmaf(w, xv.y, acc[cc].y);
            acc[cc].z = fmaf(w, xv.z, acc[cc].z);
            acc[cc].w = fmaf(w, xv.w, acc[cc].w);
        }
    }
    float ssq = 0.f;
#pragma unroll
    for (int cc = 0; cc < 4; ++cc) {
        const int c = ct * 4 + cc;
        const float bias = bp[l * 32 + c];
        acc[cc].x += bias; acc[cc].y += bias; acc[cc].z += bias; acc[cc].w += bias;
        ssq += acc[cc].x * acc[cc].x + acc[cc].y * acc[cc].y
             + acc[cc].z * acc[cc].z + acc[cc].w * acc[cc].w;
        *(float4*)(U + (size_t)b * 131072 + (size_t)(l * 32 + c) * 1024 + n) = acc[cc];
    }
    __shared__ float red[256];
    red[t] = ssq;
    __syncthreads();
    for (int s = 128; s > 0; s >>= 1) {
        if (t < s) red[t] += red[t + s];
        __syncthreads();
    }
    if (t == 0) atomicAdd(&SS[b * 4 + l], red[0]);
}

// ---------------------------------------------------------------------------
// K2: P2 flat = U flat * scale(b, l) ; scale = sqrt(ss)/(1+ss), l = flatidx>>15
// grid 512 blocks x 256 thr, float4 per thread (131072 float4 total)
__global__ void k_p2(const float* __restrict__ U, const float* __restrict__ SS,
                     float* __restrict__ P2)
{
    const int idx = blockIdx.x * 256 + threadIdx.x;   // float4 index
    const int b = idx >> 15;                          // 32768 float4 per b
    const int f4b = idx & 32767;
    const int l = f4b >> 13;                          // (f4b*4)>>15
    const float ss = SS[b * 4 + l];
    const float sc = sqrtf(ss) / (1.f + ss);
    float4 v = ((const float4*)U)[idx];
    v.x *= sc; v.y *= sc; v.z *= sc; v.w *= sc;
    ((float4*)P2)[idx] = v;
}

// ---------------------------------------------------------------------------
// K3: Cw[b][ju][q] = softmax_j(Bg[b][i][:])[j] * Wg[i][j][u][k]
//     ju=j*32+u, q=k*32+i.  grid (64, 4 b), 256 thr, 4 elems each (float4)
__global__ void k_cw(const float* __restrict__ Bg, const float* __restrict__ Wg,
                     float* __restrict__ Cw)
{
    const int xb = blockIdx.x, b = blockIdx.y;
    const int t = threadIdx.x;
    __shared__ float cls[32 * 16];
    if (t < 32) {
        float vals[16];
        float mx = -1e30f;
        for (int j = 0; j < 16; ++j) { vals[j] = Bg[b * 512 + t * 16 + j]; mx = fmaxf(mx, vals[j]); }
        float sum = 0.f;
        for (int j = 0; j < 16; ++j) { vals[j] = expf(vals[j] - mx); sum += vals[j]; }
        const float inv = 1.f / sum;
        for (int j = 0; j < 16; ++j) cls[t * 16 + j] = vals[j] * inv;
    }
    __syncthreads();
    const int e0 = xb * 1024 + t * 4;
    const int ju = e0 >> 7;
    const int j = ju >> 5, u = ju & 31;
    const int q = e0 & 127;
    const int k = q >> 5, i0 = q & 31;
    float4 r;
    r.x = cls[(i0 + 0) * 16 + j] * Wg[(((i0 + 0) * 16 + j) * 32 + u) * 4 + k];
    r.y = cls[(i0 + 1) * 16 + j] * Wg[(((i0 + 1) * 16 + j) * 32 + u) * 4 + k];
    r.z = cls[(i0 + 2) * 16 + j] * Wg[(((i0 + 2) * 16 + j) * 32 + u) * 4 + k];
    r.w = cls[(i0 + 3) * 16 + j] * Wg[(((i0 + 3) * 16 + j) * 32 + u) * 4 + k];
    ((float4*)Cw)[(b * 65536 + e0) >> 2] = r;
}

// ---------------------------------------------------------------------------
// K4: S[b][m][ju] = sum_q P2[b][m][q] * Cw[b][ju][q]
// LDS tiled 64m x 64ju, K in 2 chunks of 64, pad 65 for bank-conflict freedom
// grid (16 mt, 8 jt, 4 b), 256 thr, each 4x4 accumulators
__global__ void k_smatmul(const float* __restrict__ P2, const float* __restrict__ Cw,
                          float* __restrict__ S)
{
    __shared__ float Pt[64 * 65];
    __shared__ float Ct[64 * 65];
    const int mt = blockIdx.x, jt = blockIdx.y, b = blockIdx.z;
    const int t = threadIdx.x;
    const int tj = t & 15, tm = t >> 4;
    float acc[4][4] = {};
    const float* P2b = P2 + (size_t)b * 131072 + (size_t)mt * 64 * 128;
    const float* Cwb = Cw + (size_t)b * 65536 + (size_t)jt * 64 * 128;
    for (int kc = 0; kc < 2; ++kc) {
        for (int x = t; x < 64 * 64; x += 256) {
            const int r = x >> 6, c = x & 63;
            Pt[r * 65 + c] = P2b[r * 128 + kc * 64 + c];
            Ct[r * 65 + c] = Cwb[r * 128 + kc * 64 + c];
        }
        __syncthreads();
        for (int q = 0; q < 64; ++q) {
            float pv[4], cv[4];
#pragma unroll
            for (int mm = 0; mm < 4; ++mm) pv[mm] = Pt[(tm * 4 + mm) * 65 + q];
#pragma unroll
            for (int jj = 0; jj < 4; ++jj) cv[jj] = Ct[(tj * 4 + jj) * 65 + q];
#pragma unroll
            for (int mm = 0; mm < 4; ++mm)
#pragma unroll
                for (int jj = 0; jj < 4; ++jj)
                    acc[mm][jj] = fmaf(pv[mm], cv[jj], acc[mm][jj]);
        }
        __syncthreads();
    }
#pragma unroll
    for (int mm = 0; mm < 4; ++mm) {
        float4 w = make_float4(acc[mm][0], acc[mm][1], acc[mm][2], acc[mm][3]);
        *(float4*)(S + (size_t)b * 524288 + (size_t)(mt * 64 + tm * 4 + mm) * 512
                     + jt * 64 + tj * 4) = w;
    }
}

// ---------------------------------------------------------------------------
// K5: squash over J in place: mag[m,u] = sum_j S[m][j*32+u]^2
// grid (128, 4 b), 256 thr: thread = (ml=t>>5, u=t&31), 8 m per block
__global__ void k_squash(float* __restrict__ S)
{
    const int t = threadIdx.x;
    const int u = t & 31, ml = t >> 5;
    const int m = blockIdx.x * 8 + ml;
    const int b = blockIdx.y;
    float* row = S + (size_t)b * 524288 + (size_t)m * 512;
    float sv[16];
    float mag = 0.f;
#pragma unroll
    for (int j = 0; j < 16; ++j) { sv[j] = row[j * 32 + u]; mag = fmaf(sv[j], sv[j], mag); }
    const float sc = sqrtf(mag) / (1.f + mag);
#pragma unroll
    for (int j = 0; j < 16; ++j) row[j * 32 + u] = sv[j] * sc;
}

// ---------------------------------------------------------------------------
// K6: T[q][jv] = sum_m P2[m][q]*V[m][jv] for a (32q x 64jv) tile, then fold
// bu[i,j] += (1/1024) * sum_{u,k} Wg[i,j,u,k]*T[k*32+i][j*32+u] into Bg (atomic)
// grid (4 kt, 8 jt, 4 b), 256 thr (tq=t>>5 in 0..7 -> 4 q each; tjv=t&31 -> 2 jv)
__global__ void k_tbu(const float* __restrict__ P2, const float* __restrict__ V,
                      const float* __restrict__ Wg, float* __restrict__ Bg)
{
    __shared__ float Ps[64 * 33];
    __shared__ float Vs[64 * 65];
    __shared__ float bup[64];
    const int kt = blockIdx.x, jt = blockIdx.y, b = blockIdx.z;
    const int t = threadIdx.x;
    if (t < 64) bup[t] = 0.f;
    const int tjv = t & 31, tq = t >> 5;
    float acc[4][2] = {};
    for (int mc = 0; mc < 16; ++mc) {
        for (int x = t; x < 64 * 32; x += 256) {
            const int r = x >> 5, cq = x & 31;
            Ps[r * 33 + cq] = P2[(size_t)b * 131072 + (size_t)(mc * 64 + r) * 128 + kt * 32 + cq];
        }
        for (int x = t; x < 64 * 64; x += 256) {
            const int r = x >> 6, cj = x & 63;
            Vs[r * 65 + cj] = V[(size_t)b * 524288 + (size_t)(mc * 64 + r) * 512 + jt * 64 + cj];
        }
        __syncthreads();
        for (int m = 0; m < 64; ++m) {
            float vv[2];
            vv[0] = Vs[m * 65 + tjv * 2];
            vv[1] = Vs[m * 65 + tjv * 2 + 1];
            float pv[4];
#pragma unroll
            for (int qi = 0; qi < 4; ++qi) pv[qi] = Ps[m * 33 + tq * 4 + qi];
#pragma unroll
            for (int qi = 0; qi < 4; ++qi) {
                acc[qi][0] = fmaf(pv[qi], vv[0], acc[qi][0]);
                acc[qi][1] = fmaf(pv[qi], vv[1], acc[qi][1]);
            }
        }
        __syncthreads();
    }
    const int j_loc = tjv >> 4;
    const int j = jt * 2 + j_loc;
#pragma unroll
    for (int qi = 0; qi < 4; ++qi) {
        const int i = tq * 4 + qi;
        float s = 0.f;
#pragma unroll
        for (int ji = 0; ji < 2; ++ji) {
            const int u = (tjv * 2 + ji) & 31;
            s = fmaf(Wg[((i * 16 + j) * 32 + u) * 4 + kt], acc[qi][ji], s);
        }
        atomicAdd(&bup[i * 2 + j_loc], s);
    }
    __syncthreads();
    if (t < 64) {
        const int i = t >> 1, jl = t & 1;
        atomicAdd(&Bg[b * 512 + i * 16 + jt * 2 + jl], bup[t] * (1.f / 1024.f));
    }
}

// ---------------------------------------------------------------------------
// K7: G[b][jv] = (1/1024) sum_m V[b][m][jv]   grid (8 mt, 4 b), 256 thr
__global__ void k_gmean(const float* __restrict__ V, float* __restrict__ G)
{
    const int t = threadIdx.x;
    const int b = blockIdx.y;
    const int m0 = blockIdx.x * 128;
    for (int half = 0; half < 2; ++half) {
        const int jv = half * 256 + t;
        float s = 0.f;
        for (int m = 0; m < 128; ++m)
            s += V[(size_t)b * 524288 + (size_t)(m0 + m) * 512 + jv];
        atomicAdd(&G[b * 512 + jv], s * (1.f / 1024.f));
    }
}

// ---------------------------------------------------------------------------
// K8: per-example tail: attention score (t-independent!), condensed, u_hat_a,
//     3-iter routing with M collapsed to 1 (all rows identical). grid 4 x 256
__global__ void k_final(const float* __restrict__ G, const float* __restrict__ Wa,
                        const float* __restrict__ Ws, float* __restrict__ VA)
{
    const int b = blockIdx.x;
    const int t = threadIdx.x;
    __shared__ float g[512], cond[512], uh[8192], ba[256], cc[256], sbuf[512];
    __shared__ float msc[32], score[16], red[16];
    g[t] = G[b * 512 + t];
    g[t + 256] = G[b * 512 + 256 + t];
    ba[t] = 0.f;
    __syncthreads();
    if (t < 16) {
        float s = 0.f;
        for (int u = 0; u < 32; ++u) s = fmaf(g[t * 32 + u], Wa[u], s);
        red[t] = s;
    }
    __syncthreads();
    if (t == 0) {
        float mx = -1e30f;
        for (int j = 0; j < 16; ++j) mx = fmaxf(mx, red[j]);
        float sum = 0.f;
        for (int j = 0; j < 16; ++j) { score[j] = expf(red[j] - mx); sum += score[j]; }
        const float inv = 1.f / sum;
        for (int j = 0; j < 16; ++j) score[j] *= inv;
    }
    __syncthreads();
    cond[t] = g[t] * score[t >> 5];
    cond[t + 256] = g[t + 256] * score[(t + 256) >> 5];
    __syncthreads();
    // uh[i*512 + j*32 + u] = sum_k Ws[i][j][u][k] * cond[i*32+k]
    for (int r = 0; r < 32; ++r) {
        const int e = r * 256 + t;
        const int i = e >> 9, jj = (e >> 5) & 15, u = e & 31;
        const float* wr = Ws + (size_t)((i * 16 + jj) * 32 + u) * 32;
        float s = 0.f;
        for (int k = 0; k < 32; ++k) s = fmaf(wr[k], cond[i * 32 + k], s);
        uh[e] = s;
    }
    __syncthreads();
    for (int it = 0; it < 3; ++it) {
        if (t < 16) {
            float mx = -1e30f;
            for (int j = 0; j < 16; ++j) mx = fmaxf(mx, ba[t * 16 + j]);
            float sum = 0.f;
            for (int j = 0; j < 16; ++j) { cc[t * 16 + j] = expf(ba[t * 16 + j] - mx); sum += cc[t * 16 + j]; }
            const float inv = 1.f / sum;
            for (int j = 0; j < 16; ++j) cc[t * 16 + j] *= inv;
        }
        __syncthreads();
        for (int h = 0; h < 2; ++h) {
            const int e = h * 256 + t;
            const int j = e >> 5;
            float s = 0.f;
            for (int i = 0; i < 16; ++i) s = fmaf(cc[i * 16 + j], uh[i * 512 + e], s);
            sbuf[e] = s;
        }
        __syncthreads();
        if (t < 32) {
            float mg = 0.f;
            for (int j = 0; j < 16; ++j) { const float x = sbuf[j * 32 + t]; mg = fmaf(x, x, mg); }
            msc[t] = sqrtf(mg) / (1.f + mg);
        }
        __syncthreads();
        for (int h = 0; h < 2; ++h) {
            const int e = h * 256 + t;
            sbuf[e] *= msc[e & 31];
        }
        __syncthreads();
        if (it < 2) {
            const int i = t >> 4, j = t & 15;
            float s = 0.f;
            for (int u = 0; u < 32; ++u) s = fmaf(uh[i * 512 + j * 32 + u], sbuf[j * 32 + u], s);
            ba[t] += s;
            __syncthreads();
        }
    }
    VA[b * 512 + t] = sbuf[t];
    VA[b * 512 + 256 + t] = sbuf[256 + t];
}

// ---------------------------------------------------------------------------
// K9: out[b][t][j][u] = VA[b][j*32+u]  (score is t-independent => rows identical)
// grid 1024 x 256, float4 per thread
__global__ void k_out(const float* __restrict__ VA, float* __restrict__ out)
{
    const int idx = blockIdx.x * 256 + threadIdx.x;   // float4 index, 262144 total
    const int b = idx >> 16;                          // 65536 float4 per b
    const int jv4 = idx & 127;
    ((float4*)out)[idx] = ((const float4*)VA)[b * 128 + jv4];
}

// ---------------------------------------------------------------------------
extern "C" void kernel_launch(void* const* d_in, const int* in_sizes, int n_in,
                              void* d_out, int out_size, void* d_ws, size_t ws_size,
                              hipStream_t stream)
{
    const float* X   = (const float*)d_in[0];  // graph_embed [4,4,128,1024]
    // d_in[1] = hidden — provably unused (softmax shift-invariance kills it)
    const float* Wp  = (const float*)d_in[2];  // [4,32,4,128]
    const float* bp  = (const float*)d_in[3];  // [4,32]
    const float* Wg  = (const float*)d_in[4];  // [32,16,32,4]
    const float* Wa  = (const float*)d_in[5];  // [544]
    const float* Wsp = (const float*)d_in[6];  // [16,16,32,32]
    float* out = (float*)d_out;
    float* ws = (float*)d_ws;

    float* U  = ws + OFF_U;
    float* P2 = ws + OFF_P2;
    float* S  = ws + OFF_S;
    float* Cw = ws + OFF_CW;
    float* SS = ws + OFF_SS;
    float* Bg = ws + OFF_BG;
    float* G  = ws + OFF_G;
    float* VA = ws + OFF_VA;

    // zero SS(16) + Bg(2048) + G(2048) — contiguous
    hipMemsetAsync(SS, 0, (16 + 2048 + 2048) * sizeof(float), stream);

    k_primary<<<dim3(8, 4, 4), 256, 0, stream>>>(X, Wp, bp, U, SS);
    k_p2<<<512, 256, 0, stream>>>(U, SS, P2);

    for (int it = 0; it < 3; ++it) {
        k_cw<<<dim3(64, 4), 256, 0, stream>>>(Bg, Wg, Cw);
        k_smatmul<<<dim3(16, 8, 4), 256, 0, stream>>>(P2, Cw, S);
        k_squash<<<dim3(128, 4), 256, 0, stream>>>(S);
        if (it < 2) k_tbu<<<dim3(4, 8, 4), 256, 0, stream>>>(P2, S, Wg, Bg);
    }

    k_gmean<<<dim3(8, 4), 256, 0, stream>>>(S, G);
    k_final<<<4, 256, 0, stream>>>(G, Wa, Wsp, VA);
    k_out<<<1024, 256, 0, stream>>>(VA, out);
}

// Round 2
// 294.576 us; speedup vs baseline: 1.3733x; 1.3733x over previous
//
#include <hip/hip_runtime.h>
#include <math.h>

// Problem constants: B=4, GL=4, GF=128, N=1024, CS=32, CN=16, NA=16, S=512
//
// Flat views (fp32, per b):
//  X  : [512 k][1024 n]          k = l'*128+f
//  U  : [128 c][1024 n] ; P2 view: same buffer as [1024 m][128 q], q=k*32+i,
//       with squash scale sc[l], l = m>>8  (uniform per 64/256-row tile!)
//  S/V: [1024 m][512 ju]         ju = j*32+u
//  Cw : [512 ju][128 q]

static constexpr int OFF_U  = 0;          // 524288
static constexpr int OFF_S  = 524288;     // 2097152
static constexpr int OFF_CW = 2621440;    // 262144
static constexpr int OFF_SS = 2883584;    // 16
static constexpr int OFF_BG = 2883600;    // 2048
static constexpr int OFF_G  = 2885648;    // 2048
static constexpr int OFF_VA = 2887696;    // 2048

// ---------------------------------------------------------------------------
// K1: U = Wp @ X + bp, plus per-(b,l) sum-of-squares into SS.
// LDS-tiled 64c x 64n, K=512 in 8 chunks of 64. grid (2 ct, 16 nt, 4 b).
__global__ void k_primary(const float* __restrict__ X, const float* __restrict__ Wp,
                          const float* __restrict__ bp, float* __restrict__ U,
                          float* __restrict__ SS)
{
    __shared__ float Ws[64 * 68];   // [k][c+pad]
    __shared__ float Xs[64 * 68];   // [k][n+pad]
    __shared__ float red[256];
    const int ct = blockIdx.x, nt = blockIdx.y, b = blockIdx.z;
    const int t = threadIdx.x;
    const int tn = t & 15, tc = t >> 4;
    const int c0 = ct * 64, n0 = nt * 64;
    float acc[4][4] = {};
    for (int kc = 0; kc < 8; ++kc) {
        const int k0 = kc * 64;
        const int r = t >> 4, q4 = t & 15;
#pragma unroll
        for (int rr = 0; rr < 4; ++rr) {
            // W tile 64c x 64k, transposed into Ws[k][c]
            const int c = r + rr * 16;
            const float4 wv = *(const float4*)&Wp[(size_t)(c0 + c) * 512 + k0 + q4 * 4];
            Ws[(q4 * 4 + 0) * 68 + c] = wv.x;
            Ws[(q4 * 4 + 1) * 68 + c] = wv.y;
            Ws[(q4 * 4 + 2) * 68 + c] = wv.z;
            Ws[(q4 * 4 + 3) * 68 + c] = wv.w;
            // X tile 64k x 64n, natural layout
            const int k = r + rr * 16;
            *(float4*)&Xs[k * 68 + q4 * 4] =
                *(const float4*)&X[(size_t)b * 524288 + (size_t)(k0 + k) * 1024 + n0 + q4 * 4];
        }
        __syncthreads();
        for (int k = 0; k < 64; ++k) {
            const float4 wv = *(const float4*)&Ws[k * 68 + tc * 4];
            const float4 xv = *(const float4*)&Xs[k * 68 + tn * 4];
            const float w[4] = {wv.x, wv.y, wv.z, wv.w};
            const float x[4] = {xv.x, xv.y, xv.z, xv.w};
#pragma unroll
            for (int ci = 0; ci < 4; ++ci)
#pragma unroll
                for (int ni = 0; ni < 4; ++ni)
                    acc[ci][ni] = fmaf(w[ci], x[ni], acc[ci][ni]);
        }
        __syncthreads();
    }
    float ssq = 0.f;
#pragma unroll
    for (int ci = 0; ci < 4; ++ci) {
        const int c = c0 + tc * 4 + ci;
        const float bv = bp[c];
#pragma unroll
        for (int ni = 0; ni < 4; ++ni) {
            acc[ci][ni] += bv;
            ssq = fmaf(acc[ci][ni], acc[ci][ni], ssq);
        }
        *(float4*)&U[(size_t)b * 131072 + (size_t)c * 1024 + n0 + tn * 4] =
            make_float4(acc[ci][0], acc[ci][1], acc[ci][2], acc[ci][3]);
    }
    red[t] = ssq;
    __syncthreads();
    // two independent halves: t<128 -> l=ct*2, t>=128 -> l=ct*2+1
    for (int s = 64; s > 0; s >>= 1) {
        if ((t & 127) < s) red[t] += red[t + s];
        __syncthreads();
    }
    if (t == 0)   atomicAdd(&SS[b * 4 + ct * 2], red[0]);
    if (t == 128) atomicAdd(&SS[b * 4 + ct * 2 + 1], red[128]);
}

// ---------------------------------------------------------------------------
// K3: Cw[b][ju][q] = softmax_j(Bg[b][i][:])[j] * Wg[i][j][u][k]; ju=j*32+u, q=k*32+i
__global__ void k_cw(const float* __restrict__ Bg, const float* __restrict__ Wg,
                     float* __restrict__ Cw)
{
    const int xb = blockIdx.x, b = blockIdx.y;
    const int t = threadIdx.x;
    __shared__ float cls[32 * 16];
    if (t < 32) {
        float vals[16];
        float mx = -1e30f;
        for (int j = 0; j < 16; ++j) { vals[j] = Bg[b * 512 + t * 16 + j]; mx = fmaxf(mx, vals[j]); }
        float sum = 0.f;
        for (int j = 0; j < 16; ++j) { vals[j] = expf(vals[j] - mx); sum += vals[j]; }
        const float inv = 1.f / sum;
        for (int j = 0; j < 16; ++j) cls[t * 16 + j] = vals[j] * inv;
    }
    __syncthreads();
    const int e0 = xb * 1024 + t * 4;
    const int ju = e0 >> 7;
    const int j = ju >> 5, u = ju & 31;
    const int q = e0 & 127;
    const int k = q >> 5, i0 = q & 31;
    float4 r;
    r.x = cls[(i0 + 0) * 16 + j] * Wg[(((i0 + 0) * 16 + j) * 32 + u) * 4 + k];
    r.y = cls[(i0 + 1) * 16 + j] * Wg[(((i0 + 1) * 16 + j) * 32 + u) * 4 + k];
    r.z = cls[(i0 + 2) * 16 + j] * Wg[(((i0 + 2) * 16 + j) * 32 + u) * 4 + k];
    r.w = cls[(i0 + 3) * 16 + j] * Wg[(((i0 + 3) * 16 + j) * 32 + u) * 4 + k];
    ((float4*)Cw)[(b * 65536 + e0) >> 2] = r;
}

// ---------------------------------------------------------------------------
// K4: S[b][m][ju] = sum_q (U[m][q]*sc[m>>8]) * Cw[ju][q]
// sc uniform per block: l = mt>>2. grid (16 mt, 8 jt, 4 b), 64x64 tiles.
__global__ void k_smatmul(const float* __restrict__ U, const float* __restrict__ SS,
                          const float* __restrict__ Cw, float* __restrict__ S)
{
    __shared__ float Pt[64 * 65];
    __shared__ float Ct[64 * 65];
    const int mt = blockIdx.x, jt = blockIdx.y, b = blockIdx.z;
    const int t = threadIdx.x;
    const int tj = t & 15, tm = t >> 4;
    const float ss = SS[b * 4 + (mt >> 2)];
    const float sc = sqrtf(ss) / (1.f + ss);
    float acc[4][4] = {};
    const float* Ub  = U  + (size_t)b * 131072 + (size_t)mt * 64 * 128;
    const float* Cwb = Cw + (size_t)b * 65536  + (size_t)jt * 64 * 128;
    for (int kc = 0; kc < 2; ++kc) {
        for (int x = t; x < 64 * 64; x += 256) {
            const int r = x >> 6, c = x & 63;
            Pt[r * 65 + c] = Ub[r * 128 + kc * 64 + c] * sc;
            Ct[r * 65 + c] = Cwb[r * 128 + kc * 64 + c];
        }
        __syncthreads();
        for (int q = 0; q < 64; ++q) {
            float pv[4], cv[4];
#pragma unroll
            for (int mm = 0; mm < 4; ++mm) pv[mm] = Pt[(tm * 4 + mm) * 65 + q];
#pragma unroll
            for (int jj = 0; jj < 4; ++jj) cv[jj] = Ct[(tj * 4 + jj) * 65 + q];
#pragma unroll
            for (int mm = 0; mm < 4; ++mm)
#pragma unroll
                for (int jj = 0; jj < 4; ++jj)
                    acc[mm][jj] = fmaf(pv[mm], cv[jj], acc[mm][jj]);
        }
        __syncthreads();
    }
#pragma unroll
    for (int mm = 0; mm < 4; ++mm) {
        float4 w = make_float4(acc[mm][0], acc[mm][1], acc[mm][2], acc[mm][3]);
        *(float4*)(S + (size_t)b * 524288 + (size_t)(mt * 64 + tm * 4 + mm) * 512
                     + jt * 64 + tj * 4) = w;
    }
}

// ---------------------------------------------------------------------------
// K5: squash over J in place: mag[m,u] = sum_j S[m][j*32+u]^2
__global__ void k_squash(float* __restrict__ S)
{
    const int t = threadIdx.x;
    const int u = t & 31, ml = t >> 5;
    const int m = blockIdx.x * 8 + ml;
    const int b = blockIdx.y;
    float* row = S + (size_t)b * 524288 + (size_t)m * 512;
    float sv[16];
    float mag = 0.f;
#pragma unroll
    for (int j = 0; j < 16; ++j) { sv[j] = row[j * 32 + u]; mag = fmaf(sv[j], sv[j], mag); }
    const float sc = sqrtf(mag) / (1.f + mag);
#pragma unroll
    for (int j = 0; j < 16; ++j) row[j * 32 + u] = sv[j] * sc;
}

// ---------------------------------------------------------------------------
// K6: partial T over m-chunk (256 m) contracted immediately with Wg into Bg.
// grid (4 kt, 8 jt, 16 z=mc*4+b). sc uniform per block: l = mc.
// Epilogue: shfl-xor(width 16) reduction, 64 device atomics per block.
__global__ void k_tbu(const float* __restrict__ U, const float* __restrict__ SS,
                      const float* __restrict__ V, const float* __restrict__ Wg,
                      float* __restrict__ Bg)
{
    __shared__ float Ps[64 * 33];
    __shared__ float Vs[64 * 65];
    const int kt = blockIdx.x, jt = blockIdx.y;
    const int mc = blockIdx.z >> 2, b = blockIdx.z & 3;
    const int t = threadIdx.x;
    const int tjv = t & 31, tq = t >> 5;
    const float ss = SS[b * 4 + mc];
    const float sc = sqrtf(ss) / (1.f + ss);
    float acc[4][2] = {};
    for (int ch = 0; ch < 4; ++ch) {
        const int m0 = mc * 256 + ch * 64;
        for (int x = t; x < 64 * 32; x += 256) {
            const int r = x >> 5, cq = x & 31;
            Ps[r * 33 + cq] = U[(size_t)b * 131072 + (size_t)(m0 + r) * 128 + kt * 32 + cq] * sc;
        }
        for (int x = t; x < 64 * 64; x += 256) {
            const int r = x >> 6, cj = x & 63;
            Vs[r * 65 + cj] = V[(size_t)b * 524288 + (size_t)(m0 + r) * 512 + jt * 64 + cj];
        }
        __syncthreads();
        for (int m = 0; m < 64; ++m) {
            const float vv0 = Vs[m * 65 + tjv * 2];
            const float vv1 = Vs[m * 65 + tjv * 2 + 1];
            float pv[4];
#pragma unroll
            for (int qi = 0; qi < 4; ++qi) pv[qi] = Ps[m * 33 + tq * 4 + qi];
#pragma unroll
            for (int qi = 0; qi < 4; ++qi) {
                acc[qi][0] = fmaf(pv[qi], vv0, acc[qi][0]);
                acc[qi][1] = fmaf(pv[qi], vv1, acc[qi][1]);
            }
        }
        __syncthreads();
    }
    const int j_loc = tjv >> 4;
    const int j = jt * 2 + j_loc;
#pragma unroll
    for (int qi = 0; qi < 4; ++qi) {
        const int i = tq * 4 + qi;
        float s = 0.f;
#pragma unroll
        for (int ji = 0; ji < 2; ++ji) {
            const int u = (tjv * 2 + ji) & 31;
            s = fmaf(Wg[((i * 16 + j) * 32 + u) * 4 + kt], acc[qi][ji], s);
        }
#pragma unroll
        for (int off = 1; off < 16; off <<= 1) s += __shfl_xor(s, off, 16);
        if ((t & 15) == 0) atomicAdd(&Bg[b * 512 + i * 16 + j], s * (1.f / 1024.f));
    }
}

// ---------------------------------------------------------------------------
// K7: G[b][jv] = (1/1024) sum_m V[b][m][jv]   grid (32 mt, 4 b)
__global__ void k_gmean(const float* __restrict__ V, float* __restrict__ G)
{
    const int t = threadIdx.x;
    const int b = blockIdx.y;
    const int m0 = blockIdx.x * 32;
    for (int half = 0; half < 2; ++half) {
        const int jv = half * 256 + t;
        float s = 0.f;
        for (int m = 0; m < 32; ++m)
            s += V[(size_t)b * 524288 + (size_t)(m0 + m) * 512 + jv];
        atomicAdd(&G[b * 512 + jv], s * (1.f / 1024.f));
    }
}

// ---------------------------------------------------------------------------
// K8: per-example tail (score is t-independent; hidden drops out of softmax)
__global__ void k_final(const float* __restrict__ G, const float* __restrict__ Wa,
                        const float* __restrict__ Ws, float* __restrict__ VA)
{
    const int b = blockIdx.x;
    const int t = threadIdx.x;
    __shared__ float g[512], cond[512], uh[8192], ba[256], cc[256], sbuf[512];
    __shared__ float msc[32], score[16], red[16];
    g[t] = G[b * 512 + t];
    g[t + 256] = G[b * 512 + 256 + t];
    ba[t] = 0.f;
    __syncthreads();
    if (t < 16) {
        float s = 0.f;
        for (int u = 0; u < 32; ++u) s = fmaf(g[t * 32 + u], Wa[u], s);
        red[t] = s;
    }
    __syncthreads();
    if (t == 0) {
        float mx = -1e30f;
        for (int j = 0; j < 16; ++j) mx = fmaxf(mx, red[j]);
        float sum = 0.f;
        for (int j = 0; j < 16; ++j) { score[j] = expf(red[j] - mx); sum += score[j]; }
        const float inv = 1.f / sum;
        for (int j = 0; j < 16; ++j) score[j] *= inv;
    }
    __syncthreads();
    cond[t] = g[t] * score[t >> 5];
    cond[t + 256] = g[t + 256] * score[(t + 256) >> 5];
    __syncthreads();
    for (int r = 0; r < 32; ++r) {
        const int e = r * 256 + t;
        const int i = e >> 9, jj = (e >> 5) & 15, u = e & 31;
        const float* wr = Ws + (size_t)((i * 16 + jj) * 32 + u) * 32;
        float s = 0.f;
        for (int k = 0; k < 32; ++k) s = fmaf(wr[k], cond[i * 32 + k], s);
        uh[e] = s;
    }
    __syncthreads();
    for (int it = 0; it < 3; ++it) {
        if (t < 16) {
            float mx = -1e30f;
            for (int j = 0; j < 16; ++j) mx = fmaxf(mx, ba[t * 16 + j]);
            float sum = 0.f;
            for (int j = 0; j < 16; ++j) { cc[t * 16 + j] = expf(ba[t * 16 + j] - mx); sum += cc[t * 16 + j]; }
            const float inv = 1.f / sum;
            for (int j = 0; j < 16; ++j) cc[t * 16 + j] *= inv;
        }
        __syncthreads();
        for (int h = 0; h < 2; ++h) {
            const int e = h * 256 + t;
            const int j = e >> 5;
            float s = 0.f;
            for (int i = 0; i < 16; ++i) s = fmaf(cc[i * 16 + j], uh[i * 512 + e], s);
            sbuf[e] = s;
        }
        __syncthreads();
        if (t < 32) {
            float mg = 0.f;
            for (int j = 0; j < 16; ++j) { const float x = sbuf[j * 32 + t]; mg = fmaf(x, x, mg); }
            msc[t] = sqrtf(mg) / (1.f + mg);
        }
        __syncthreads();
        for (int h = 0; h < 2; ++h) {
            const int e = h * 256 + t;
            sbuf[e] *= msc[e & 31];
        }
        __syncthreads();
        if (it < 2) {
            const int i = t >> 4, j = t & 15;
            float s = 0.f;
            for (int u = 0; u < 32; ++u) s = fmaf(uh[i * 512 + j * 32 + u], sbuf[j * 32 + u], s);
            ba[t] += s;
            __syncthreads();
        }
    }
    VA[b * 512 + t] = sbuf[t];
    VA[b * 512 + 256 + t] = sbuf[256 + t];
}

// ---------------------------------------------------------------------------
// K9: broadcast VA to all 512 rows per example
__global__ void k_out(const float* __restrict__ VA, float* __restrict__ out)
{
    const int idx = blockIdx.x * 256 + threadIdx.x;
    const int b = idx >> 16;
    const int jv4 = idx & 127;
    ((float4*)out)[idx] = ((const float4*)VA)[b * 128 + jv4];
}

// ---------------------------------------------------------------------------
extern "C" void kernel_launch(void* const* d_in, const int* in_sizes, int n_in,
                              void* d_out, int out_size, void* d_ws, size_t ws_size,
                              hipStream_t stream)
{
    const float* X   = (const float*)d_in[0];
    // d_in[1] = hidden — provably unused (softmax shift-invariance kills it)
    const float* Wp  = (const float*)d_in[2];
    const float* bp  = (const float*)d_in[3];
    const float* Wg  = (const float*)d_in[4];
    const float* Wa  = (const float*)d_in[5];
    const float* Wsp = (const float*)d_in[6];
    float* out = (float*)d_out;
    float* ws = (float*)d_ws;

    float* U  = ws + OFF_U;
    float* S  = ws + OFF_S;
    float* Cw = ws + OFF_CW;
    float* SS = ws + OFF_SS;
    float* Bg = ws + OFF_BG;
    float* G  = ws + OFF_G;
    float* VA = ws + OFF_VA;

    hipMemsetAsync(SS, 0, (16 + 2048 + 2048) * sizeof(float), stream);

    k_primary<<<dim3(2, 16, 4), 256, 0, stream>>>(X, Wp, bp, U, SS);

    for (int it = 0; it < 3; ++it) {
        k_cw<<<dim3(64, 4), 256, 0, stream>>>(Bg, Wg, Cw);
        k_smatmul<<<dim3(16, 8, 4), 256, 0, stream>>>(U, SS, Cw, S);
        k_squash<<<dim3(128, 4), 256, 0, stream>>>(S);
        if (it < 2) k_tbu<<<dim3(4, 8, 16), 256, 0, stream>>>(U, SS, S, Wg, Bg);
    }

    k_gmean<<<dim3(32, 4), 256, 0, stream>>>(S, G);
    k_final<<<4, 256, 0, stream>>>(G, Wa, Wsp, VA);
    k_out<<<1024, 256, 0, stream>>>(VA, out);
}

// Round 3
// 271.614 us; speedup vs baseline: 1.4894x; 1.0845x over previous
//
#include <hip/hip_runtime.h>
#include <math.h>

// Problem constants: B=4, GL=4, GF=128, N=1024, CS=32, CN=16, NA=16, S=512
//
// Flat views (fp32, per b):
//  X  : [512 k][1024 n]
//  U  : [128 c][1024 n] ; P2 view: [1024 m][128 q], q=k*32+i, scale sc[l], l=m>>8
//  S  : [1024 m][512 ju]  (UNsquashed; MS holds squash scales)   ju=j*32+u
//  MS : [1024 m][32 u]    squash scale per (m,u)
//  UH : [8192]            u_hat for aspect routing, e = i*512 + j*32 + u

static constexpr int OFF_U  = 0;          // 524288
static constexpr int OFF_S  = 524288;     // 2097152 (also Upart[4][524288])
static constexpr int OFF_SS = 2621440;    // 16
static constexpr int OFF_BG = 2621456;    // 2048
static constexpr int OFF_G  = 2623504;    // 2048
static constexpr int OFF_VA = 2625552;    // 2048
static constexpr int OFF_MS = 2627600;    // 131072
static constexpr int OFF_UH = 2758672;    // 32768

// ---------------------------------------------------------------------------
// K1a: partial U over K-window of 128: Upart[ks] = Wp[:, ks*128:+128] @ X[ks*128:+128, :]
// W tile (64c x 128k) preloaded to LDS transposed (pad 68 -> conflict-free b128 reads),
// X streamed straight from global — NO barriers in the K loop.
// grid (2 ct, 16 nt, 16 z: b=z>>2, ks=z&3), 256 thr, 4c x 4n outputs each.
__global__ void k_primary_part(const float* __restrict__ X, const float* __restrict__ Wp,
                               float* __restrict__ Upart)
{
    __shared__ float Wt[128 * 68];
    const int ct = blockIdx.x, nt = blockIdx.y;
    const int b = blockIdx.z >> 2, ks = blockIdx.z & 3;
    const int t = threadIdx.x;
    const int tn = t & 15, tc = t >> 4;
    const int c0 = ct * 64, n0 = nt * 64;
#pragma unroll
    for (int i = 0; i < 8; ++i) {
        const int idx = t + i * 256;
        const int c = idx >> 5, k4 = idx & 31;
        const float4 wv = *(const float4*)&Wp[(size_t)(c0 + c) * 512 + ks * 128 + k4 * 4];
        Wt[(k4 * 4 + 0) * 68 + c] = wv.x;
        Wt[(k4 * 4 + 1) * 68 + c] = wv.y;
        Wt[(k4 * 4 + 2) * 68 + c] = wv.z;
        Wt[(k4 * 4 + 3) * 68 + c] = wv.w;
    }
    __syncthreads();
    float acc[4][4] = {};
    const float* Xp = X + (size_t)b * 524288 + (size_t)(ks * 128) * 1024 + n0 + tn * 4;
#pragma unroll 4
    for (int k = 0; k < 128; ++k) {
        const float4 xv = *(const float4*)(Xp + (size_t)k * 1024);
        const float4 wv = *(const float4*)&Wt[k * 68 + tc * 4];
        const float w[4] = {wv.x, wv.y, wv.z, wv.w};
        const float x[4] = {xv.x, xv.y, xv.z, xv.w};
#pragma unroll
        for (int ci = 0; ci < 4; ++ci)
#pragma unroll
            for (int ni = 0; ni < 4; ++ni)
                acc[ci][ni] = fmaf(w[ci], x[ni], acc[ci][ni]);
    }
    float* up = Upart + (size_t)ks * 524288 + (size_t)b * 131072;
#pragma unroll
    for (int ci = 0; ci < 4; ++ci)
        *(float4*)&up[(size_t)(c0 + tc * 4 + ci) * 1024 + n0 + tn * 4] =
            make_float4(acc[ci][0], acc[ci][1], acc[ci][2], acc[ci][3]);
}

// ---------------------------------------------------------------------------
// K1b: U = sum_ks Upart[ks] + bp, and SS[b][l] = sum of squares.
// grid 128 (b=blk>>5, c-group=blk&31 -> 4 c rows, single l per block), 256 thr.
__global__ void k_reduceU(const float* __restrict__ Upart, const float* __restrict__ bp,
                          float* __restrict__ U, float* __restrict__ SS)
{
    __shared__ float red[256];
    const int blk = blockIdx.x, t = threadIdx.x;
    const int b = blk >> 5, cg = blk & 31;
    float ssq = 0.f;
#pragma unroll
    for (int i = 0; i < 4; ++i) {
        const int c = cg * 4 + i;
        const int f4 = b * 32768 + c * 256 + t;
        float4 s = ((const float4*)Upart)[f4];
#pragma unroll
        for (int ks = 1; ks < 4; ++ks) {
            const float4 p = ((const float4*)Upart)[ks * 131072 + f4];
            s.x += p.x; s.y += p.y; s.z += p.z; s.w += p.w;
        }
        const float bv = bp[c];
        s.x += bv; s.y += bv; s.z += bv; s.w += bv;
        ssq = fmaf(s.x, s.x, ssq); ssq = fmaf(s.y, s.y, ssq);
        ssq = fmaf(s.z, s.z, ssq); ssq = fmaf(s.w, s.w, ssq);
        ((float4*)U)[f4] = s;
    }
    red[t] = ssq;
    __syncthreads();
    for (int s = 128; s > 0; s >>= 1) {
        if (t < s) red[t] += red[t + s];
        __syncthreads();
    }
    if (t == 0) atomicAdd(&SS[b * 4 + (cg >> 3)], red[0]);
}

// ---------------------------------------------------------------------------
// K4: S[b][m][ju] = sum_q (U[m][q]*sc) * (cls[i][j]*Wg[i][j][u][k])   (Cw built in-LDS)
// grid (16 mt, 8 jt, 4 b), 64x64 tiles, K=128 in 2 chunks.
__global__ void k_smatmul(const float* __restrict__ U, const float* __restrict__ SS,
                          const float* __restrict__ Bg, const float* __restrict__ Wg,
                          float* __restrict__ S)
{
    __shared__ float Pt[64 * 65];
    __shared__ float Ct[64 * 65];
    __shared__ float cls[512];
    const int mt = blockIdx.x, jt = blockIdx.y, b = blockIdx.z;
    const int t = threadIdx.x;
    const int tj = t & 15, tm = t >> 4;
    if (t < 32) {
        float vals[16];
        float mx = -1e30f;
        for (int j = 0; j < 16; ++j) { vals[j] = Bg[b * 512 + t * 16 + j]; mx = fmaxf(mx, vals[j]); }
        float sum = 0.f;
        for (int j = 0; j < 16; ++j) { vals[j] = expf(vals[j] - mx); sum += vals[j]; }
        const float inv = 1.f / sum;
        for (int j = 0; j < 16; ++j) cls[t * 16 + j] = vals[j] * inv;
    }
    const float ss = SS[b * 4 + (mt >> 2)];
    const float sc = sqrtf(ss) / (1.f + ss);
    float acc[4][4] = {};
    const float* Ub = U + (size_t)b * 131072 + (size_t)mt * 64 * 128;
    __syncthreads();
    for (int kc = 0; kc < 2; ++kc) {
        for (int x = t; x < 64 * 64; x += 256) {
            const int r = x >> 6, cq = x & 63;
            Pt[r * 65 + cq] = Ub[r * 128 + kc * 64 + cq] * sc;
            const int q = kc * 64 + cq;
            const int i = q & 31, kk = q >> 5;
            const int ju = jt * 64 + r;
            const int j = ju >> 5, u = ju & 31;
            Ct[r * 65 + cq] = cls[i * 16 + j] * Wg[((i * 16 + j) * 32 + u) * 4 + kk];
        }
        __syncthreads();
        for (int q = 0; q < 64; ++q) {
            float pv[4], cv[4];
#pragma unroll
            for (int mm = 0; mm < 4; ++mm) pv[mm] = Pt[(tm * 4 + mm) * 65 + q];
#pragma unroll
            for (int jj = 0; jj < 4; ++jj) cv[jj] = Ct[(tj * 4 + jj) * 65 + q];
#pragma unroll
            for (int mm = 0; mm < 4; ++mm)
#pragma unroll
                for (int jj = 0; jj < 4; ++jj)
                    acc[mm][jj] = fmaf(pv[mm], cv[jj], acc[mm][jj]);
        }
        __syncthreads();
    }
#pragma unroll
    for (int mm = 0; mm < 4; ++mm) {
        float4 w = make_float4(acc[mm][0], acc[mm][1], acc[mm][2], acc[mm][3]);
        *(float4*)(S + (size_t)b * 524288 + (size_t)(mt * 64 + tm * 4 + mm) * 512
                     + jt * 64 + tj * 4) = w;
    }
}

// ---------------------------------------------------------------------------
// K5: MS[b][m][u] = squash scale over J of S (no S rewrite). grid (128, 4 b).
__global__ void k_mag(const float* __restrict__ S, float* __restrict__ MS)
{
    const int t = threadIdx.x;
    const int u = t & 31, ml = t >> 5;
    const int m = blockIdx.x * 8 + ml;
    const int b = blockIdx.y;
    const float* row = S + (size_t)b * 524288 + (size_t)m * 512;
    float mag = 0.f;
#pragma unroll
    for (int j = 0; j < 16; ++j) { const float v = row[j * 32 + u]; mag = fmaf(v, v, mag); }
    MS[b * 32768 + m * 32 + u] = sqrtf(mag) / (1.f + mag);
}

// ---------------------------------------------------------------------------
// K6: b-update. T-partials over 256 m contracted with Wg into Bg.
// V = S*MS applied on load. grid (4 kt, 8 jt, 16 z=mc*4+b).
__global__ void k_tbu(const float* __restrict__ U, const float* __restrict__ SS,
                      const float* __restrict__ S, const float* __restrict__ MS,
                      const float* __restrict__ Wg, float* __restrict__ Bg)
{
    __shared__ float Ps[64 * 33];
    __shared__ float Vs[64 * 65];
    const int kt = blockIdx.x, jt = blockIdx.y;
    const int mc = blockIdx.z >> 2, b = blockIdx.z & 3;
    const int t = threadIdx.x;
    const int tjv = t & 31, tq = t >> 5;
    const float ss = SS[b * 4 + mc];
    const float sc = sqrtf(ss) / (1.f + ss);
    float acc[4][2] = {};
    for (int ch = 0; ch < 4; ++ch) {
        const int m0 = mc * 256 + ch * 64;
        for (int x = t; x < 64 * 32; x += 256) {
            const int r = x >> 5, cq = x & 31;
            Ps[r * 33 + cq] = U[(size_t)b * 131072 + (size_t)(m0 + r) * 128 + kt * 32 + cq] * sc;
        }
        for (int x = t; x < 64 * 64; x += 256) {
            const int r = x >> 6, cj = x & 63;
            Vs[r * 65 + cj] = S[(size_t)b * 524288 + (size_t)(m0 + r) * 512 + jt * 64 + cj]
                            * MS[b * 32768 + (m0 + r) * 32 + (cj & 31)];
        }
        __syncthreads();
        for (int m = 0; m < 64; ++m) {
            const float vv0 = Vs[m * 65 + tjv * 2];
            const float vv1 = Vs[m * 65 + tjv * 2 + 1];
            float pv[4];
#pragma unroll
            for (int qi = 0; qi < 4; ++qi) pv[qi] = Ps[m * 33 + tq * 4 + qi];
#pragma unroll
            for (int qi = 0; qi < 4; ++qi) {
                acc[qi][0] = fmaf(pv[qi], vv0, acc[qi][0]);
                acc[qi][1] = fmaf(pv[qi], vv1, acc[qi][1]);
            }
        }
        __syncthreads();
    }
    const int j_loc = tjv >> 4;
    const int j = jt * 2 + j_loc;
#pragma unroll
    for (int qi = 0; qi < 4; ++qi) {
        const int i = tq * 4 + qi;
        float s = 0.f;
#pragma unroll
        for (int ji = 0; ji < 2; ++ji) {
            const int u = (tjv * 2 + ji) & 31;
            s = fmaf(Wg[((i * 16 + j) * 32 + u) * 4 + kt], acc[qi][ji], s);
        }
#pragma unroll
        for (int off = 1; off < 16; off <<= 1) s += __shfl_xor(s, off, 16);
        if ((t & 15) == 0) atomicAdd(&Bg[b * 512 + i * 16 + j], s * (1.f / 1024.f));
    }
}

// ---------------------------------------------------------------------------
// K7: G[b][jv] = (1/1024) sum_m S[b][m][jv]*MS[b][m][jv&31]   grid (32 mt, 4 b)
__global__ void k_gmean(const float* __restrict__ S, const float* __restrict__ MS,
                        float* __restrict__ G)
{
    const int t = threadIdx.x;
    const int b = blockIdx.y;
    const int m0 = blockIdx.x * 32;
    for (int half = 0; half < 2; ++half) {
        const int jv = half * 256 + t;
        const int u = jv & 31;
        float s = 0.f;
        for (int m = 0; m < 32; ++m)
            s = fmaf(S[(size_t)b * 524288 + (size_t)(m0 + m) * 512 + jv],
                     MS[b * 32768 + (m0 + m) * 32 + u], s);
        atomicAdd(&G[b * 512 + jv], s * (1.f / 1024.f));
    }
}

// ---------------------------------------------------------------------------
// K8a: UH[b][e] = sum_k Ws[e][k] * cond[b][i*32+k], e = i*512+j*32+u.
// score/cond recomputed per block (tiny). grid (8 slices, 4 b), 256 thr, 4 e each.
__global__ void k_uhat(const float* __restrict__ G, const float* __restrict__ Wa,
                       const float* __restrict__ Ws, float* __restrict__ UH)
{
    const int b = blockIdx.y;
    const int t = threadIdx.x;
    __shared__ float g[512], cond[512], score[16], red[16];
    g[t] = G[b * 512 + t];
    g[t + 256] = G[b * 512 + 256 + t];
    __syncthreads();
    if (t < 16) {
        float s = 0.f;
        for (int u = 0; u < 32; ++u) s = fmaf(g[t * 32 + u], Wa[u], s);
        red[t] = s;
    }
    __syncthreads();
    if (t == 0) {
        float mx = -1e30f;
        for (int j = 0; j < 16; ++j) mx = fmaxf(mx, red[j]);
        float sum = 0.f;
        for (int j = 0; j < 16; ++j) { score[j] = expf(red[j] - mx); sum += score[j]; }
        const float inv = 1.f / sum;
        for (int j = 0; j < 16; ++j) score[j] *= inv;
    }
    __syncthreads();
    cond[t] = g[t] * score[t >> 5];
    cond[t + 256] = g[t + 256] * score[(t + 256) >> 5];
    __syncthreads();
    const int e0 = blockIdx.x * 1024 + t * 4;
    const int i = e0 >> 9;
    const float* cp = cond + i * 32;
    const float* wp = Ws + (size_t)e0 * 32;
    float res[4];
#pragma unroll
    for (int jj = 0; jj < 4; ++jj) {
        float s = 0.f;
#pragma unroll
        for (int k8 = 0; k8 < 8; ++k8) {
            const float4 w = *(const float4*)(wp + jj * 32 + k8 * 4);
            s = fmaf(w.x, cp[k8 * 4 + 0], s);
            s = fmaf(w.y, cp[k8 * 4 + 1], s);
            s = fmaf(w.z, cp[k8 * 4 + 2], s);
            s = fmaf(w.w, cp[k8 * 4 + 3], s);
        }
        res[jj] = s;
    }
    ((float4*)UH)[(b * 8192 + e0) >> 2] = make_float4(res[0], res[1], res[2], res[3]);
}

// ---------------------------------------------------------------------------
// K8b: 3-iter aspect routing on LDS-resident UH. grid 4, 256 thr.
__global__ void k_route(const float* __restrict__ UH, float* __restrict__ VA)
{
    const int b = blockIdx.x;
    const int t = threadIdx.x;
    __shared__ float uh[8192], ba[256], cc[256], sbuf[512], msc[32];
#pragma unroll
    for (int i = 0; i < 8; ++i)
        ((float4*)uh)[i * 256 + t] = ((const float4*)UH)[b * 2048 + i * 256 + t];
    ba[t] = 0.f;
    __syncthreads();
    for (int it = 0; it < 3; ++it) {
        if (t < 16) {
            float mx = -1e30f;
            for (int j = 0; j < 16; ++j) mx = fmaxf(mx, ba[t * 16 + j]);
            float sum = 0.f;
            for (int j = 0; j < 16; ++j) { cc[t * 16 + j] = expf(ba[t * 16 + j] - mx); sum += cc[t * 16 + j]; }
            const float inv = 1.f / sum;
            for (int j = 0; j < 16; ++j) cc[t * 16 + j] *= inv;
        }
        __syncthreads();
        for (int h = 0; h < 2; ++h) {
            const int e = h * 256 + t;
            const int j = e >> 5;
            float s = 0.f;
            for (int i = 0; i < 16; ++i) s = fmaf(cc[i * 16 + j], uh[i * 512 + e], s);
            sbuf[e] = s;
        }
        __syncthreads();
        if (t < 32) {
            float mg = 0.f;
            for (int j = 0; j < 16; ++j) { const float x = sbuf[j * 32 + t]; mg = fmaf(x, x, mg); }
            msc[t] = sqrtf(mg) / (1.f + mg);
        }
        __syncthreads();
        for (int h = 0; h < 2; ++h) {
            const int e = h * 256 + t;
            sbuf[e] *= msc[e & 31];
        }
        __syncthreads();
        if (it < 2) {
            const int i = t >> 4, j = t & 15;
            float s = 0.f;
            for (int u = 0; u < 32; ++u) s = fmaf(uh[i * 512 + j * 32 + u], sbuf[j * 32 + u], s);
            ba[t] += s;
            __syncthreads();
        }
    }
    VA[b * 512 + t] = sbuf[t];
    VA[b * 512 + 256 + t] = sbuf[256 + t];
}

// ---------------------------------------------------------------------------
// K9: broadcast VA to all 512 rows per example
__global__ void k_out(const float* __restrict__ VA, float* __restrict__ out)
{
    const int idx = blockIdx.x * 256 + threadIdx.x;
    const int b = idx >> 16;
    const int jv4 = idx & 127;
    ((float4*)out)[idx] = ((const float4*)VA)[b * 128 + jv4];
}

// ---------------------------------------------------------------------------
extern "C" void kernel_launch(void* const* d_in, const int* in_sizes, int n_in,
                              void* d_out, int out_size, void* d_ws, size_t ws_size,
                              hipStream_t stream)
{
    const float* X   = (const float*)d_in[0];
    // d_in[1] = hidden — provably unused (softmax shift-invariance kills it)
    const float* Wp  = (const float*)d_in[2];
    const float* bp  = (const float*)d_in[3];
    const float* Wg  = (const float*)d_in[4];
    const float* Wa  = (const float*)d_in[5];
    const float* Wsp = (const float*)d_in[6];
    float* out = (float*)d_out;
    float* ws = (float*)d_ws;

    float* U  = ws + OFF_U;
    float* S  = ws + OFF_S;     // also Upart[4] before k_reduceU
    float* SS = ws + OFF_SS;
    float* Bg = ws + OFF_BG;
    float* G  = ws + OFF_G;
    float* VA = ws + OFF_VA;
    float* MS = ws + OFF_MS;
    float* UH = ws + OFF_UH;

    // zero SS(16) + Bg(2048) + G(2048) — contiguous
    hipMemsetAsync(SS, 0, (16 + 2048 + 2048) * sizeof(float), stream);

    k_primary_part<<<dim3(2, 16, 16), 256, 0, stream>>>(X, Wp, S);
    k_reduceU<<<128, 256, 0, stream>>>(S, bp, U, SS);

    for (int it = 0; it < 3; ++it) {
        k_smatmul<<<dim3(16, 8, 4), 256, 0, stream>>>(U, SS, Bg, Wg, S);
        k_mag<<<dim3(128, 4), 256, 0, stream>>>(S, MS);
        if (it < 2) k_tbu<<<dim3(4, 8, 16), 256, 0, stream>>>(U, SS, S, MS, Wg, Bg);
    }

    k_gmean<<<dim3(32, 4), 256, 0, stream>>>(S, MS, G);
    k_uhat<<<dim3(8, 4), 256, 0, stream>>>(G, Wa, Wsp, UH);
    k_route<<<4, 256, 0, stream>>>(UH, VA);
    k_out<<<1024, 256, 0, stream>>>(VA, out);
}

// Round 4
// 230.117 us; speedup vs baseline: 1.7580x; 1.1803x over previous
//
#include <hip/hip_runtime.h>
#include <math.h>

// Problem constants: B=4, GL=4, GF=128, N=1024, CS=32, CN=16, NA=16, S=512
//
// Flat views (fp32, per b):
//  X  : [512 k][1024 n]
//  U  : [128 c][1024 n] ; P2 view: [1024 m][128 q], q=k*32+i, scale sc[l], l=m>>8
//  S  : [1024 m][512 ju]  (UNsquashed; MS holds squash scales)   ju=j*32+u
//  MS : [1024 m][32 u]    squash scale per (m,u)
//  UH : [8192]            u_hat for aspect routing, e = i*512 + j*32 + u

static constexpr int OFF_U  = 0;          // 524288
static constexpr int OFF_S  = 524288;     // 2097152 (also Upart[4][524288])
static constexpr int OFF_SS = 2621440;    // 16
static constexpr int OFF_BG = 2621456;    // 2048
static constexpr int OFF_G  = 2623504;    // 2048
static constexpr int OFF_VA = 2625552;    // 2048
static constexpr int OFF_MS = 2627600;    // 131072
static constexpr int OFF_UH = 2758672;    // 32768

// ---------------------------------------------------------------------------
// K1a: partial U over K-window of 128: Upart[ks] = Wp[:, ks*128:+128] @ X[ks*128:+128, :]
// grid (2 ct, 16 nt, 16 z: b=z>>2, ks=z&3), 256 thr, 4c x 4n outputs each.
__global__ void k_primary_part(const float* __restrict__ X, const float* __restrict__ Wp,
                               float* __restrict__ Upart)
{
    __shared__ float Wt[128 * 68];
    const int ct = blockIdx.x, nt = blockIdx.y;
    const int b = blockIdx.z >> 2, ks = blockIdx.z & 3;
    const int t = threadIdx.x;
    const int tn = t & 15, tc = t >> 4;
    const int c0 = ct * 64, n0 = nt * 64;
#pragma unroll
    for (int i = 0; i < 8; ++i) {
        const int idx = t + i * 256;
        const int c = idx >> 5, k4 = idx & 31;
        const float4 wv = *(const float4*)&Wp[(size_t)(c0 + c) * 512 + ks * 128 + k4 * 4];
        Wt[(k4 * 4 + 0) * 68 + c] = wv.x;
        Wt[(k4 * 4 + 1) * 68 + c] = wv.y;
        Wt[(k4 * 4 + 2) * 68 + c] = wv.z;
        Wt[(k4 * 4 + 3) * 68 + c] = wv.w;
    }
    __syncthreads();
    float acc[4][4] = {};
    const float* Xp = X + (size_t)b * 524288 + (size_t)(ks * 128) * 1024 + n0 + tn * 4;
#pragma unroll 4
    for (int k = 0; k < 128; ++k) {
        const float4 xv = *(const float4*)(Xp + (size_t)k * 1024);
        const float4 wv = *(const float4*)&Wt[k * 68 + tc * 4];
        const float w[4] = {wv.x, wv.y, wv.z, wv.w};
        const float x[4] = {xv.x, xv.y, xv.z, xv.w};
#pragma unroll
        for (int ci = 0; ci < 4; ++ci)
#pragma unroll
            for (int ni = 0; ni < 4; ++ni)
                acc[ci][ni] = fmaf(w[ci], x[ni], acc[ci][ni]);
    }
    float* up = Upart + (size_t)ks * 524288 + (size_t)b * 131072;
#pragma unroll
    for (int ci = 0; ci < 4; ++ci)
        *(float4*)&up[(size_t)(c0 + tc * 4 + ci) * 1024 + n0 + tn * 4] =
            make_float4(acc[ci][0], acc[ci][1], acc[ci][2], acc[ci][3]);
}

// ---------------------------------------------------------------------------
// K1b: U = sum_ks Upart[ks] + bp, and SS[b][l] = sum of squares. grid 128.
__global__ void k_reduceU(const float* __restrict__ Upart, const float* __restrict__ bp,
                          float* __restrict__ U, float* __restrict__ SS)
{
    __shared__ float red[256];
    const int blk = blockIdx.x, t = threadIdx.x;
    const int b = blk >> 5, cg = blk & 31;
    float ssq = 0.f;
#pragma unroll
    for (int i = 0; i < 4; ++i) {
        const int c = cg * 4 + i;
        const int f4 = b * 32768 + c * 256 + t;
        float4 s = ((const float4*)Upart)[f4];
#pragma unroll
        for (int ks = 1; ks < 4; ++ks) {
            const float4 p = ((const float4*)Upart)[ks * 131072 + f4];
            s.x += p.x; s.y += p.y; s.z += p.z; s.w += p.w;
        }
        const float bv = bp[c];
        s.x += bv; s.y += bv; s.z += bv; s.w += bv;
        ssq = fmaf(s.x, s.x, ssq); ssq = fmaf(s.y, s.y, ssq);
        ssq = fmaf(s.z, s.z, ssq); ssq = fmaf(s.w, s.w, ssq);
        ((float4*)U)[f4] = s;
    }
    red[t] = ssq;
    __syncthreads();
    for (int s = 128; s > 0; s >>= 1) {
        if (t < s) red[t] += red[t + s];
        __syncthreads();
    }
    if (t == 0) atomicAdd(&SS[b * 4 + (cg >> 3)], red[0]);
}

// ---------------------------------------------------------------------------
// K4: S[b][m][ju] = sum_q (U[m][q]*sc) * (cls[i][j]*Wg[i][j][u][k])
// grid (16 mt, 8 jt, 4 b), 64x64 tiles, K=128 in 2 chunks.
__global__ void k_smatmul(const float* __restrict__ U, const float* __restrict__ SS,
                          const float* __restrict__ Bg, const float* __restrict__ Wg,
                          float* __restrict__ S)
{
    __shared__ float Pt[64 * 65];
    __shared__ float Ct[64 * 65];
    __shared__ float cls[512];
    const int mt = blockIdx.x, jt = blockIdx.y, b = blockIdx.z;
    const int t = threadIdx.x;
    const int tj = t & 15, tm = t >> 4;
    if (t < 32) {
        float vals[16];
        float mx = -1e30f;
        for (int j = 0; j < 16; ++j) { vals[j] = Bg[b * 512 + t * 16 + j]; mx = fmaxf(mx, vals[j]); }
        float sum = 0.f;
        for (int j = 0; j < 16; ++j) { vals[j] = expf(vals[j] - mx); sum += vals[j]; }
        const float inv = 1.f / sum;
        for (int j = 0; j < 16; ++j) cls[t * 16 + j] = vals[j] * inv;
    }
    const float ss = SS[b * 4 + (mt >> 2)];
    const float sc = sqrtf(ss) / (1.f + ss);
    float acc[4][4] = {};
    const float* Ub = U + (size_t)b * 131072 + (size_t)mt * 64 * 128;
    __syncthreads();
    for (int kc = 0; kc < 2; ++kc) {
        for (int x = t; x < 64 * 64; x += 256) {
            const int r = x >> 6, cq = x & 63;
            Pt[r * 65 + cq] = Ub[r * 128 + kc * 64 + cq] * sc;
            const int q = kc * 64 + cq;
            const int i = q & 31, kk = q >> 5;
            const int ju = jt * 64 + r;
            const int j = ju >> 5, u = ju & 31;
            Ct[r * 65 + cq] = cls[i * 16 + j] * Wg[((i * 16 + j) * 32 + u) * 4 + kk];
        }
        __syncthreads();
        for (int q = 0; q < 64; ++q) {
            float pv[4], cv[4];
#pragma unroll
            for (int mm = 0; mm < 4; ++mm) pv[mm] = Pt[(tm * 4 + mm) * 65 + q];
#pragma unroll
            for (int jj = 0; jj < 4; ++jj) cv[jj] = Ct[(tj * 4 + jj) * 65 + q];
#pragma unroll
            for (int mm = 0; mm < 4; ++mm)
#pragma unroll
                for (int jj = 0; jj < 4; ++jj)
                    acc[mm][jj] = fmaf(pv[mm], cv[jj], acc[mm][jj]);
        }
        __syncthreads();
    }
#pragma unroll
    for (int mm = 0; mm < 4; ++mm) {
        float4 w = make_float4(acc[mm][0], acc[mm][1], acc[mm][2], acc[mm][3]);
        *(float4*)(S + (size_t)b * 524288 + (size_t)(mt * 64 + tm * 4 + mm) * 512
                     + jt * 64 + tj * 4) = w;
    }
}

// ---------------------------------------------------------------------------
// K5: MS[b][m][u] = squash scale over J of S. grid (128, 4 b).
__global__ void k_mag(const float* __restrict__ S, float* __restrict__ MS)
{
    const int t = threadIdx.x;
    const int u = t & 31, ml = t >> 5;
    const int m = blockIdx.x * 8 + ml;
    const int b = blockIdx.y;
    const float* row = S + (size_t)b * 524288 + (size_t)m * 512;
    float mag = 0.f;
#pragma unroll
    for (int j = 0; j < 16; ++j) { const float v = row[j * 32 + u]; mag = fmaf(v, v, mag); }
    MS[b * 32768 + m * 32 + u] = sqrtf(mag) / (1.f + mag);
}

// ---------------------------------------------------------------------------
// K5b (last iter): mag + mean fused: G[b][jv] = (1/1024) sum_m S*msc.
// grid (32 mt, 4 b); thread = (u, mlg), 4 m rows each.
__global__ void k_maggmean(const float* __restrict__ S, float* __restrict__ G)
{
    __shared__ float gacc[512];
    const int t = threadIdx.x;
    gacc[t] = 0.f; gacc[t + 256] = 0.f;
    const int u = t & 31, mlg = t >> 5;
    const int b = blockIdx.y;
    const int m0 = blockIdx.x * 32 + mlg * 4;
    float preg[16];
#pragma unroll
    for (int j = 0; j < 16; ++j) preg[j] = 0.f;
    __syncthreads();
#pragma unroll
    for (int mi = 0; mi < 4; ++mi) {
        const float* row = S + (size_t)b * 524288 + (size_t)(m0 + mi) * 512;
        float sv[16];
        float mag = 0.f;
#pragma unroll
        for (int j = 0; j < 16; ++j) { sv[j] = row[j * 32 + u]; mag = fmaf(sv[j], sv[j], mag); }
        const float msc = sqrtf(mag) / (1.f + mag);
#pragma unroll
        for (int j = 0; j < 16; ++j) preg[j] = fmaf(sv[j], msc, preg[j]);
    }
#pragma unroll
    for (int j = 0; j < 16; ++j) atomicAdd(&gacc[j * 32 + u], preg[j]);
    __syncthreads();
    atomicAdd(&G[b * 512 + t], gacc[t] * (1.f / 1024.f));
    atomicAdd(&G[b * 512 + 256 + t], gacc[t + 256] * (1.f / 1024.f));
}

// ---------------------------------------------------------------------------
// K6: b-update, kt merged: each block computes full 128q x 64jv T-tile over a
// 64-m chunk, contracts with Wg into Bg. grid (8 jt, 16 mc, 4 b) = 512 blocks.
// Thread: tq=t&31 (4 q each), tjv=t>>5 (8 jv each), acc[4][8].
__global__ void k_tbu(const float* __restrict__ U, const float* __restrict__ SS,
                      const float* __restrict__ S, const float* __restrict__ MS,
                      const float* __restrict__ Wg, float* __restrict__ Bg)
{
    __shared__ float Ps[64 * 132];   // [m][q], pad 132
    __shared__ float Vs[64 * 68];    // [m][jv], pad 68
    __shared__ float bup[64];        // [i][j_loc]
    const int jt = blockIdx.x, mc = blockIdx.y, b = blockIdx.z;
    const int t = threadIdx.x;
    const int tq = t & 31, tjv = t >> 5;
    const int m0 = mc * 64;
    if (t < 64) bup[t] = 0.f;
    const float ss = SS[b * 4 + (mc >> 2)];
    const float sc = sqrtf(ss) / (1.f + ss);
    // stage P2 tile (64m x 128q) scaled
#pragma unroll
    for (int i = 0; i < 8; ++i) {
        const int f4 = t + i * 256;          // 0..2047
        const int r = f4 >> 5, q4 = f4 & 31;
        float4 v = *(const float4*)&U[(size_t)b * 131072 + (size_t)(m0 + r) * 128 + q4 * 4];
        v.x *= sc; v.y *= sc; v.z *= sc; v.w *= sc;
        *(float4*)&Ps[r * 132 + q4 * 4] = v;
    }
    // stage V tile (64m x 64jv) = S * MS
#pragma unroll
    for (int i = 0; i < 4; ++i) {
        const int f4 = t + i * 256;          // 0..1023
        const int r = f4 >> 4, c4 = f4 & 15;
        const int m = m0 + r;
        float4 v = *(const float4*)&S[(size_t)b * 524288 + (size_t)m * 512 + jt * 64 + c4 * 4];
        const int ub = (c4 * 4) & 31;
        const float* msp = MS + b * 32768 + m * 32;
        v.x *= msp[ub + 0]; v.y *= msp[ub + 1]; v.z *= msp[ub + 2]; v.w *= msp[ub + 3];
        *(float4*)&Vs[r * 68 + c4 * 4] = v;
    }
    __syncthreads();
    float acc[4][8] = {};
#pragma unroll 2
    for (int m = 0; m < 64; ++m) {
        const float4 p4 = *(const float4*)&Ps[m * 132 + tq * 4];
        const float4 va = *(const float4*)&Vs[m * 68 + tjv * 8];
        const float4 vb = *(const float4*)&Vs[m * 68 + tjv * 8 + 4];
        const float pv[4] = {p4.x, p4.y, p4.z, p4.w};
        const float vv[8] = {va.x, va.y, va.z, va.w, vb.x, vb.y, vb.z, vb.w};
#pragma unroll
        for (int qi = 0; qi < 4; ++qi)
#pragma unroll
            for (int ji = 0; ji < 8; ++ji)
                acc[qi][ji] = fmaf(pv[qi], vv[ji], acc[qi][ji]);
    }
    // epilogue: contract with Wg. thread's q = tq*4+qi -> k = tq>>3, i = (tq&7)*4+qi
    // thread's jv = tjv*8+ji -> j = jt*2 + (tjv>>2), u = (tjv&3)*8+ji
    const int k = tq >> 3;
    const int j_loc = tjv >> 2;          // bit 7 of t
    const int j = jt * 2 + j_loc;
    const int u0 = (tjv & 3) * 8;
#pragma unroll
    for (int qi = 0; qi < 4; ++qi) {
        const int i = (tq & 7) * 4 + qi;
        const float* wp = Wg + ((i * 16 + j) * 32) * 4 + k;
        float s = 0.f;
#pragma unroll
        for (int ji = 0; ji < 8; ++ji)
            s = fmaf(wp[(u0 + ji) * 4], acc[qi][ji], s);
        // reduce over k (bits 3,4) and u-group bit (bit 5) in-wave
        s += __shfl_xor(s, 8);
        s += __shfl_xor(s, 16);
        s += __shfl_xor(s, 32);
        if ((t & 56) == 0) atomicAdd(&bup[i * 2 + j_loc], s);
    }
    __syncthreads();
    if (t < 64) {
        const int ii = t >> 1, jl = t & 1;
        atomicAdd(&Bg[b * 512 + ii * 16 + jt * 2 + jl], bup[t] * (1.f / 1024.f));
    }
}

// ---------------------------------------------------------------------------
// K8a: UH[b][e] = sum_k Ws[e][k] * cond[b][i*32+k]. grid (8 slices, 4 b).
__global__ void k_uhat(const float* __restrict__ G, const float* __restrict__ Wa,
                       const float* __restrict__ Ws, float* __restrict__ UH)
{
    const int b = blockIdx.y;
    const int t = threadIdx.x;
    __shared__ float g[512], cond[512], score[16], red[16];
    g[t] = G[b * 512 + t];
    g[t + 256] = G[b * 512 + 256 + t];
    __syncthreads();
    if (t < 16) {
        float s = 0.f;
        for (int u = 0; u < 32; ++u) s = fmaf(g[t * 32 + u], Wa[u], s);
        red[t] = s;
    }
    __syncthreads();
    if (t == 0) {
        float mx = -1e30f;
        for (int j = 0; j < 16; ++j) mx = fmaxf(mx, red[j]);
        float sum = 0.f;
        for (int j = 0; j < 16; ++j) { score[j] = expf(red[j] - mx); sum += score[j]; }
        const float inv = 1.f / sum;
        for (int j = 0; j < 16; ++j) score[j] *= inv;
    }
    __syncthreads();
    cond[t] = g[t] * score[t >> 5];
    cond[t + 256] = g[t + 256] * score[(t + 256) >> 5];
    __syncthreads();
    const int e0 = blockIdx.x * 1024 + t * 4;
    const int i = e0 >> 9;
    const float* cp = cond + i * 32;
    const float* wp = Ws + (size_t)e0 * 32;
    float res[4];
#pragma unroll
    for (int jj = 0; jj < 4; ++jj) {
        float s = 0.f;
#pragma unroll
        for (int k8 = 0; k8 < 8; ++k8) {
            const float4 w = *(const float4*)(wp + jj * 32 + k8 * 4);
            s = fmaf(w.x, cp[k8 * 4 + 0], s);
            s = fmaf(w.y, cp[k8 * 4 + 1], s);
            s = fmaf(w.z, cp[k8 * 4 + 2], s);
            s = fmaf(w.w, cp[k8 * 4 + 3], s);
        }
        res[jj] = s;
    }
    ((float4*)UH)[(b * 8192 + e0) >> 2] = make_float4(res[0], res[1], res[2], res[3]);
}

// ---------------------------------------------------------------------------
// K8b: 3-iter aspect routing on LDS-resident UH. grid 4, 256 thr.
__global__ void k_route(const float* __restrict__ UH, float* __restrict__ VA)
{
    const int b = blockIdx.x;
    const int t = threadIdx.x;
    __shared__ float uh[8192], ba[256], cc[256], sbuf[512], msc[32];
#pragma unroll
    for (int i = 0; i < 8; ++i)
        ((float4*)uh)[i * 256 + t] = ((const float4*)UH)[b * 2048 + i * 256 + t];
    ba[t] = 0.f;
    __syncthreads();
    for (int it = 0; it < 3; ++it) {
        if (t < 16) {
            float mx = -1e30f;
            for (int j = 0; j < 16; ++j) mx = fmaxf(mx, ba[t * 16 + j]);
            float sum = 0.f;
            for (int j = 0; j < 16; ++j) { cc[t * 16 + j] = expf(ba[t * 16 + j] - mx); sum += cc[t * 16 + j]; }
            const float inv = 1.f / sum;
            for (int j = 0; j < 16; ++j) cc[t * 16 + j] *= inv;
        }
        __syncthreads();
        for (int h = 0; h < 2; ++h) {
            const int e = h * 256 + t;
            const int j = e >> 5;
            float s = 0.f;
            for (int i = 0; i < 16; ++i) s = fmaf(cc[i * 16 + j], uh[i * 512 + e], s);
            sbuf[e] = s;
        }
        __syncthreads();
        if (t < 32) {
            float mg = 0.f;
            for (int j = 0; j < 16; ++j) { const float x = sbuf[j * 32 + t]; mg = fmaf(x, x, mg); }
            msc[t] = sqrtf(mg) / (1.f + mg);
        }
        __syncthreads();
        for (int h = 0; h < 2; ++h) {
            const int e = h * 256 + t;
            sbuf[e] *= msc[e & 31];
        }
        __syncthreads();
        if (it < 2) {
            const int i = t >> 4, j = t & 15;
            float s = 0.f;
            for (int u = 0; u < 32; ++u) s = fmaf(uh[i * 512 + j * 32 + u], sbuf[j * 32 + u], s);
            ba[t] += s;
            __syncthreads();
        }
    }
    VA[b * 512 + t] = sbuf[t];
    VA[b * 512 + 256 + t] = sbuf[256 + t];
}

// ---------------------------------------------------------------------------
// K9: broadcast VA to all 512 rows per example
__global__ void k_out(const float* __restrict__ VA, float* __restrict__ out)
{
    const int idx = blockIdx.x * 256 + threadIdx.x;
    const int b = idx >> 16;
    const int jv4 = idx & 127;
    ((float4*)out)[idx] = ((const float4*)VA)[b * 128 + jv4];
}

// ---------------------------------------------------------------------------
extern "C" void kernel_launch(void* const* d_in, const int* in_sizes, int n_in,
                              void* d_out, int out_size, void* d_ws, size_t ws_size,
                              hipStream_t stream)
{
    const float* X   = (const float*)d_in[0];
    // d_in[1] = hidden — provably unused (softmax shift-invariance kills it)
    const float* Wp  = (const float*)d_in[2];
    const float* bp  = (const float*)d_in[3];
    const float* Wg  = (const float*)d_in[4];
    const float* Wa  = (const float*)d_in[5];
    const float* Wsp = (const float*)d_in[6];
    float* out = (float*)d_out;
    float* ws = (float*)d_ws;

    float* U  = ws + OFF_U;
    float* S  = ws + OFF_S;     // also Upart[4] before k_reduceU
    float* SS = ws + OFF_SS;
    float* Bg = ws + OFF_BG;
    float* G  = ws + OFF_G;
    float* VA = ws + OFF_VA;
    float* MS = ws + OFF_MS;
    float* UH = ws + OFF_UH;

    // zero SS(16) + Bg(2048) + G(2048) — contiguous
    hipMemsetAsync(SS, 0, (16 + 2048 + 2048) * sizeof(float), stream);

    k_primary_part<<<dim3(2, 16, 16), 256, 0, stream>>>(X, Wp, S);
    k_reduceU<<<128, 256, 0, stream>>>(S, bp, U, SS);

    for (int it = 0; it < 3; ++it) {
        k_smatmul<<<dim3(16, 8, 4), 256, 0, stream>>>(U, SS, Bg, Wg, S);
        if (it < 2) {
            k_mag<<<dim3(128, 4), 256, 0, stream>>>(S, MS);
            k_tbu<<<dim3(8, 16, 4), 256, 0, stream>>>(U, SS, S, MS, Wg, Bg);
        } else {
            k_maggmean<<<dim3(32, 4), 256, 0, stream>>>(S, G);
        }
    }

    k_uhat<<<dim3(8, 4), 256, 0, stream>>>(G, Wa, Wsp, UH);
    k_route<<<4, 256, 0, stream>>>(UH, VA);
    k_out<<<1024, 256, 0, stream>>>(VA, out);
}